// Round 7
// baseline (99.268 us; speedup 1.0000x reference)
//
#include <hip/hip_runtime.h>
#include <math.h>

#define BB 4
#define TT 1024
#define HH 16
#define NROWS 64   // 2*BINS table rows
#define RPAD 20    // padded row floats (80 B: 16B-aligned chunks at 16w)
#define ROWS_PER_BLOCK 8

#define PI_F    3.14159265358979323846f
#define TWOPI_F 6.28318530717958647692f

typedef float f4 __attribute__((ext_vector_type(4)));

// Fused kernel, plane-quad decomposition:
// block owns (b, 8 rows); wave w owns planes h in [4w, 4w+4).
// Each lane computes bins for 16 j's; per row, the wave writes each of its 4
// plane-rows as 4 consecutive 1KB stores (4KB contiguous runs) instead of
// plane-hopping every store.
__global__ __launch_bounds__(256) void QuantizedRPE_fused_kernel(
        const float* __restrict__ coords,
        const float* __restrict__ table,
        float* __restrict__ out) {
    __shared__ float tl[NROWS][RPAD];   // [row][h]; rows 0..31 eta, 32..63 phi
    __shared__ float sre[BB];
    int tid = threadIdx.x;
    int lane = tid & 63;
    int w = tid >> 6;

    // ---- stage table: 256 x float4 covers 64 rows x 16 floats ----
    {
        f4 t4 = ((const f4*)table)[tid];
        int row = tid >> 2, col = (tid & 3) * 4;
        *(f4*)&tl[row][col] = t4;
    }

    // ---- global eta range: wave w reduces batch w (f4 = 2 coord pairs) ----
    {
        const f4* cp4 = (const f4*)coords;
        float mx = -1e30f, mn = 1e30f;
        #pragma unroll
        for (int it = 0; it < TT / 128; ++it) {
            f4 v = cp4[(size_t)w * (TT / 2) + lane + it * 64];
            mx = fmaxf(mx, fmaxf(v.x, v.z));
            mn = fminf(mn, fminf(v.x, v.z));
        }
        #pragma unroll
        for (int m = 32; m; m >>= 1) {
            mx = fmaxf(mx, __shfl_xor(mx, m));
            mn = fminf(mn, __shfl_xor(mn, m));
        }
        if (lane == 0) sre[w] = mx - mn;
    }
    __syncthreads();
    float range = fmaxf(fmaxf(fmaxf(sre[0], sre[1]), fmaxf(sre[2], sre[3])), 1e-6f);

    int b  = blockIdx.x >> 7;
    int i0 = (blockIdx.x & 127) * ROWS_PER_BLOCK;

    // j-coords for this lane's 16 j's: group c covers j = c*256 + lane*4 + {0..3}
    float ej[16], pj[16];
    #pragma unroll
    for (int c = 0; c < 4; ++c) {
        const f4* cp = (const f4*)(coords + (size_t)(b * TT + c * 256 + lane * 4) * 2);
        f4 c01 = cp[0];
        f4 c23 = cp[1];
        ej[c * 4 + 0] = c01.x; pj[c * 4 + 0] = c01.y;
        ej[c * 4 + 1] = c01.z; pj[c * 4 + 1] = c01.w;
        ej[c * 4 + 2] = c23.x; pj[c * 4 + 2] = c23.y;
        ej[c * 4 + 3] = c23.z; pj[c * 4 + 3] = c23.w;
    }

    #pragma unroll
    for (int r = 0; r < ROWS_PER_BLOCK; ++r) {
        int i = i0 + r;
        float ei  = coords[(size_t)(b * TT + i) * 2 + 0];   // block-uniform -> s_load
        float pii = coords[(size_t)(b * TT + i) * 2 + 1];

        float v[16][4];   // [j16][h-quad 4], compile-time indices after unroll
        #pragma unroll
        for (int jj = 0; jj < 16; ++jj) {
            // eta bin: same op order as reference (bit-exact, frozen)
            float re = ei - ej[jj];
            int be = (int)(re / range * 16.0f);
            be = min(max(be, -16), 15);
            int eidx = be + 16;                 // [0,32)
            // phi wrap: fmod + sign-fix == np.mod (exact)
            float ww = (pii - pj[jj]) + PI_F;
            float m = fmodf(ww, TWOPI_F);
            if (m < 0.0f) m += TWOPI_F;
            float rp = m - PI_F;
            int bp = (int)(rp / PI_F * 16.0f);
            bp = min(max(bp, -16), 15);
            int pidx = bp + 48;                 // [32,64)

            f4 a = *(const f4*)&tl[eidx][4 * w];   // this wave's 4-h chunk
            f4 p = *(const f4*)&tl[pidx][4 * w];
            v[jj][0] = a.x + p.x;
            v[jj][1] = a.y + p.y;
            v[jj][2] = a.z + p.z;
            v[jj][3] = a.w + p.w;
        }

        // wave writes its 4 plane-rows, each as 4 consecutive 1KB stores
        float* rowp = out + ((size_t)(b * HH + 4 * w) * TT + i) * TT + lane * 4;
        #pragma unroll
        for (int q = 0; q < 4; ++q) {
            float* hp = rowp + (size_t)q * TT * TT;
            #pragma unroll
            for (int c = 0; c < 4; ++c) {
                f4 sv = { v[c * 4 + 0][q], v[c * 4 + 1][q],
                          v[c * 4 + 2][q], v[c * 4 + 3][q] };
                *(f4*)(hp + c * 256) = sv;
            }
        }
    }
}

extern "C" void kernel_launch(void* const* d_in, const int* in_sizes, int n_in,
                              void* d_out, int out_size, void* d_ws, size_t ws_size,
                              hipStream_t stream) {
    const float* coords = (const float*)d_in[0];   // [4,1024,2] f32
    const float* table  = (const float*)d_in[1];   // [64,16]   f32
    float* out = (float*)d_out;                    // [4,16,1024,1024] f32
    (void)d_ws; (void)ws_size;

    QuantizedRPE_fused_kernel<<<BB * TT / ROWS_PER_BLOCK, 256, 0, stream>>>(coords, table, out);
}

// Round 8
// 49.462 us; speedup vs baseline: 2.0069x; 2.0069x over previous
//
#include <hip/hip_runtime.h>
#include <math.h>

#define BB 4
#define TT 1024
#define HH 16
#define NROWS 64   // 2*BINS table rows
#define RPAD 20    // padded row floats
#define ROWS_PER_BLOCK 8

#define PI_F    3.14159265358979323846f
#define TWOPI_F 6.28318530717958647692f

typedef float f4 __attribute__((ext_vector_type(4)));

// Plane-quad decomposition, chunked: wave w owns planes [4w,4w+4).
// Per row, 4 j-chunks of 4: compute 4 bins -> v[4][4] (16 regs) -> 4 stores.
// Each plane's write stream advances 1KB/chunk -> 4 contiguous 4KB streams
// per wave per row, with a small live set (vs R7's 96-float live set).
__global__ __launch_bounds__(256) void QuantizedRPE_fused_kernel(
        const float* __restrict__ coords,
        const float* __restrict__ table,
        float* __restrict__ out) {
    __shared__ float tl[NROWS][RPAD];   // [row][h]; rows 0..31 eta, 32..63 phi
    __shared__ float sre[BB];
    int tid = threadIdx.x;
    int lane = tid & 63;
    int w = tid >> 6;

    // ---- stage table: 256 x float4 covers 64 rows x 16 floats ----
    {
        f4 t4 = ((const f4*)table)[tid];
        int row = tid >> 2, col = (tid & 3) * 4;
        *(f4*)&tl[row][col] = t4;
    }

    // ---- global eta range: wave w reduces batch w ----
    {
        const f4* cp4 = (const f4*)coords;
        float mx = -1e30f, mn = 1e30f;
        #pragma unroll
        for (int it = 0; it < TT / 128; ++it) {
            f4 v = cp4[(size_t)w * (TT / 2) + lane + it * 64];
            mx = fmaxf(mx, fmaxf(v.x, v.z));
            mn = fminf(mn, fminf(v.x, v.z));
        }
        #pragma unroll
        for (int m = 32; m; m >>= 1) {
            mx = fmaxf(mx, __shfl_xor(mx, m));
            mn = fminf(mn, __shfl_xor(mn, m));
        }
        if (lane == 0) sre[w] = mx - mn;
    }
    __syncthreads();
    float range = fmaxf(fmaxf(fmaxf(sre[0], sre[1]), fmaxf(sre[2], sre[3])), 1e-6f);

    int b  = blockIdx.x >> 7;
    int i0 = (blockIdx.x & 127) * ROWS_PER_BLOCK;

    // j-coords for this lane's 16 j's: chunk c covers j = c*256 + lane*4 + {0..3}
    float ej[16], pj[16];
    #pragma unroll
    for (int c = 0; c < 4; ++c) {
        const f4* cp = (const f4*)(coords + (size_t)(b * TT + c * 256 + lane * 4) * 2);
        f4 c01 = cp[0];
        f4 c23 = cp[1];
        ej[c * 4 + 0] = c01.x; pj[c * 4 + 0] = c01.y;
        ej[c * 4 + 1] = c01.z; pj[c * 4 + 1] = c01.w;
        ej[c * 4 + 2] = c23.x; pj[c * 4 + 2] = c23.y;
        ej[c * 4 + 3] = c23.z; pj[c * 4 + 3] = c23.w;
    }

    #pragma unroll 1
    for (int r = 0; r < ROWS_PER_BLOCK; ++r) {
        int i = i0 + r;
        float ei  = coords[(size_t)(b * TT + i) * 2 + 0];   // block-uniform
        float pii = coords[(size_t)(b * TT + i) * 2 + 1];
        float* rowp = out + ((size_t)(b * HH + 4 * w) * TT + i) * TT + lane * 4;

        #pragma unroll
        for (int c = 0; c < 4; ++c) {
            float v[4][4];   // [jj][h-quad], 16 regs
            #pragma unroll
            for (int jj = 0; jj < 4; ++jj) {
                // eta bin: same op order as reference (bit-exact, frozen)
                float re = ei - ej[c * 4 + jj];
                int be = (int)(re / range * 16.0f);
                be = min(max(be, -16), 15);
                int eidx = be + 16;                 // [0,32)
                // phi wrap: fmod + sign-fix == np.mod (exact)
                float ww = (pii - pj[c * 4 + jj]) + PI_F;
                float m = fmodf(ww, TWOPI_F);
                if (m < 0.0f) m += TWOPI_F;
                float rp = m - PI_F;
                int bp = (int)(rp / PI_F * 16.0f);
                bp = min(max(bp, -16), 15);
                int pidx = bp + 48;                 // [32,64)

                f4 a = *(const f4*)&tl[eidx][4 * w];
                f4 p = *(const f4*)&tl[pidx][4 * w];
                v[jj][0] = a.x + p.x;
                v[jj][1] = a.y + p.y;
                v[jj][2] = a.z + p.z;
                v[jj][3] = a.w + p.w;
            }
            #pragma unroll
            for (int q = 0; q < 4; ++q) {
                f4 sv = { v[0][q], v[1][q], v[2][q], v[3][q] };
                *(f4*)(rowp + (size_t)q * TT * TT + c * 256) = sv;
            }
        }
    }
}

extern "C" void kernel_launch(void* const* d_in, const int* in_sizes, int n_in,
                              void* d_out, int out_size, void* d_ws, size_t ws_size,
                              hipStream_t stream) {
    const float* coords = (const float*)d_in[0];   // [4,1024,2] f32
    const float* table  = (const float*)d_in[1];   // [64,16]   f32
    float* out = (float*)d_out;                    // [4,16,1024,1024] f32
    (void)d_ws; (void)ws_size;

    QuantizedRPE_fused_kernel<<<BB * TT / ROWS_PER_BLOCK, 256, 0, stream>>>(coords, table, out);
}